// Round 11
// baseline (375.313 us; speedup 1.0000x reference)
//
#include <hip/hip_runtime.h>

typedef unsigned short u16;
typedef unsigned int u32;
typedef short s8v __attribute__((ext_vector_type(8)));    // 8 x bf16 bits (4 VGPRs)
typedef float f16v __attribute__((ext_vector_type(16)));  // 32x32 MFMA accumulator
typedef u32 u32x4 __attribute__((ext_vector_type(4)));

// ---------- helpers ----------
__device__ __forceinline__ u16 f2bf(float f) {
    u32 u = __float_as_uint(f);
    u += 0x7FFFu + ((u >> 16) & 1u);   // round-to-nearest-even
    return (u16)(u >> 16);
}

__device__ __forceinline__ void async_load16(const u16* g, u16* l) {
    // global -> LDS DMA, 16B per lane; LDS dest = wave-uniform base + lane*16
    __builtin_amdgcn_global_load_lds(
        (const __attribute__((address_space(1))) u32*)g,
        (__attribute__((address_space(3))) u32*)l,
        16, 0, 0);
}

// ---------- kernel 0: style (once per b, coalesced mod_w via LDS) ----------
__global__ void style_kernel(const float* __restrict__ norm_feat,  // [8][64]
                             const float* __restrict__ mod_w,      // [256][64]
                             const float* __restrict__ mod_b,      // [256]
                             float* __restrict__ style) {          // [8][256]
    __shared__ float nf[64];
    __shared__ float mw[256][65];
    const int b = blockIdx.x;
    const int tid = threadIdx.x;

    if (tid < 64) nf[tid] = norm_feat[b * 64 + tid];
    #pragma unroll
    for (int i = 0; i < 64; ++i) {
        int idx = i * 256 + tid;
        mw[idx >> 6][idx & 63] = mod_w[idx];
    }
    __syncthreads();

    float s = mod_b[tid];
    #pragma unroll 8
    for (int d = 0; d < 64; ++d) s += nf[d] * mw[tid][d];
    style[b * 256 + tid] = s;
}

// ---------- kernel 1: demod + modulated bf16 weights ----------
// grid (256 co, 8 b), 256 threads (thread = ci)
// Wmod layout for 32x32x16 fragments:
//   [b][t][cob=co>>5 (8)][cib=ci>>4 (16)][lane=(co&31)+32*((ci>>3)&1)][elem=ci&7]
// weight[co] slice staged in LDS via coalesced loads.
__global__ void modulate_kernel(const float* __restrict__ style,   // [8][256]
                                const float* __restrict__ weight,  // [256][256][9]
                                u16* __restrict__ Wmod) {
    const int co = blockIdx.x;
    const int b  = blockIdx.y;
    const int ci = threadIdx.x;

    __shared__ float wlds[2304];
    __shared__ float red[256];

    const float* wsrc = weight + (size_t)co * 2304;
    #pragma unroll
    for (int i = 0; i < 9; ++i) wlds[i * 256 + ci] = wsrc[i * 256 + ci];

    const float s = style[b * 256 + ci];
    __syncthreads();

    // per-thread 9 taps from LDS: addr stride 9, gcd(9,32)=1 -> conflict-free
    float w9[9];
    float sq = 0.f;
    #pragma unroll
    for (int t = 0; t < 9; ++t) { w9[t] = wlds[ci * 9 + t]; sq += w9[t] * w9[t]; }

    red[ci] = sq * s * s;
    __syncthreads();
    for (int off = 128; off > 0; off >>= 1) {
        if (ci < off) red[ci] += red[ci + off];
        __syncthreads();
    }
    const float scale = 1.0f / 48.0f;              // 1/sqrt(256*9)
    const float demod = rsqrtf(scale * scale * red[0] + 1e-8f);
    const float coef  = scale * s * demod;

    // t=0 base; per-t stride = 8*16*64*8 = 65536 u16
    const size_t tile = (((size_t)b * 9 * 8 + (co >> 5)) * 16 + (ci >> 4)) * 512
                      + (size_t)((co & 31) + 32 * ((ci >> 3) & 1)) * 8 + (ci & 7);
    #pragma unroll
    for (int t = 0; t < 9; ++t) {
        Wmod[tile + (size_t)t * 65536] = f2bf(w9[t] * coef);
    }
}

// ---------- kernel 2: NCHW fp32 -> blocked-NHWC bf16 (R7 LDS version) ----------
// feaT layout: [b][y][ch(16)][cg(2)][x(128)][cil(8)] bf16   (c = ch*16 + cg*8 + cil)
// grid (128 y, 4 cblk, 8 b), 256 threads — one 64-c group per block
__global__ __launch_bounds__(256) void transpose_kernel(const float* __restrict__ fea,
                                                        u16* __restrict__ feaT) {
    __shared__ float lds_t[64][132];   // row = 528B -> float4-aligned, 2-way banks
    const int y  = blockIdx.x;
    const int c0 = blockIdx.y * 64;
    const int b  = blockIdx.z;
    const int tid = threadIdx.x;

    #pragma unroll
    for (int r = 0; r < 8; ++r) {
        int i  = r * 256 + tid;       // 0..2047
        int c  = i >> 5;              // 0..63
        int x4 = i & 31;              // float4 index
        float4 v = *(const float4*)&fea[(((size_t)(b * 256 + c0 + c)) * 128 + y) * 128 + x4 * 4];
        *(float4*)&lds_t[c][x4 * 4] = v;
    }
    __syncthreads();
    #pragma unroll
    for (int jj = 0; jj < 4; ++jj) {
        int p   = jj * 256 + tid;     // 0..1023
        int x   = p & 127;
        int g   = p >> 7;             // 0..7 (granule of 8 c)
        int cb8 = g * 8;
        u32x4 wv;
        #pragma unroll
        for (int k = 0; k < 4; ++k) {
            float f0 = lds_t[cb8 + 2 * k][x];
            float f1 = lds_t[cb8 + 2 * k + 1][x];
            wv[k] = (u32)f2bf(f0) | ((u32)f2bf(f1) << 16);
        }
        int c  = c0 + cb8;
        int ch = c >> 4;
        int cg = (c >> 3) & 1;
        size_t off = (((((size_t)b * 128 + y) * 16 + ch) * 2 + cg) * 128 + x) * 8;
        *(u32x4*)&feaT[off] = wv;
    }
}

// ---------- kernel 3: MFMA conv (shift-GEMM), 32x32x16, CHUNK=32 ci ----------
// grid (64 y-pairs, 8 b), 256 threads = 4 waves (mw2 x yw2), 2 output rows/block
// R8/R10 anchor with 32-ci chunks: 18 steps (9 taps x 2 ci-halves) = 288 MFMA
// between barriers; 7 barriers instead of 15, tap-0 bubbles halved.
__global__ __launch_bounds__(256, 1) void conv_mfma(
        const u16* __restrict__ Wmod,   // fragment-ordered, see modulate_kernel
        const u16* __restrict__ feaT,   // [8][128][16][2][128][8] bf16
        float* __restrict__ out) {      // [8][256][128][128]
    // per-parity: 16384 u16 fea ([row4][cgq4][x128][8ci]) + two 16-u16 zero pads
    // (pad at 16384 for cib=0 redirects, 18432 = 16384+2048 for cib=1 redirects)
    __shared__ u16 lds[2][18448];       // 73,792 B

    // XCD swizzle: 512 wgs = 8 XCDs x 64; each XCD owns one batch b
    const int lin = blockIdx.x + 64 * blockIdx.y;
    const int nid = (lin & 7) * 64 + (lin >> 3);
    const int yp  = nid & 63;           // y-pair: rows 2*yp, 2*yp+1
    const int b   = nid >> 6;

    // chunk phase stagger (kept from R10; free)
    const int phase = ((yp >> 5) & 1) * 4;

    const int tid  = threadIdx.x;
    const int lane = tid & 63;
    const int wave = tid >> 6;          // 0..3
    const int mw   = wave & 1;          // co half (128 of 256)
    const int ywv  = wave >> 1;         // output row within pair (vector)
    const int l31  = lane & 31;
    const int l5   = lane >> 5;         // k-group (8 ci)

    // wave-uniform scalar copies (drive scalar branches for y-edge taps)
    const int yw_s   = __builtin_amdgcn_readfirstlane(ywv);
    const int y_out_s = 2 * yp + yw_s;
    const bool rokU[3] = { y_out_s > 0, true, y_out_s < 127 };

    // zero both parity pads (16 u16 at 16384 and at 18432)
    if (tid < 16) {
        lds[0][16384 + tid] = 0; lds[0][18432 + tid] = 0;
        lds[1][16384 + tid] = 0; lds[1][18432 + tid] = 0;
    }

    // ---- B-side LDS offsets (u16 units, rel. to parity base), cib=0 ----
    // step (t,cib), frag j: addr = rb[kh] + cib*2048 + j*256 + kw*8 (imm-folded)
    int rb[3], bqL[3], bqR[3];
    #pragma unroll
    for (int kh = 0; kh < 3; ++kh) {
        const int rr = ywv + kh;                      // LDS row 0..3
        const int o  = ((rr * 4 + l5) * 128 + (l31 - 1)) * 8;
        rb[kh]  = o;
        bqL[kh] = (l31 > 0)  ? o : 16384;             // x_in = -1 -> zero pad
        bqR[kh] = (l31 < 31) ? (o + 3 * 256 + 16) : 16384;  // x_in = 128 -> pad
    }

    // A-side: cob = mw*4 + i (i=0..3); strides (u16): t=65536, cob=8192, cib=512
    const u16* Abase = Wmod + (size_t)b * 9 * 65536
                            + (size_t)(mw * 4) * 8192 + (size_t)lane * 8;

    auto loadA = [&](int t, int i, int cib_g) -> s8v {
        return *(const s8v*)(Abase + (size_t)t * 65536 + (size_t)i * 8192 + (size_t)cib_g * 512);
    };

    // stage one 32-ci chunk C: 32 contiguous 1024B DMA units
    // u = [r(2b)][ch_lo(1b)][cg(1b)][xq(1b)]; wave w does u = w + 4*i, i<8
    auto stage = [&](int buf, int C) {
        u16* ldsb = &lds[buf][0];
        #pragma unroll
        for (int i = 0; i < 8; ++i) {
            int u     = wave + 4 * i;     // 0..31, wave-uniform
            int r     = u >> 3;           // 0..3
            int ch_lo = (u >> 2) & 1;
            int cg    = (u >> 1) & 1;
            int xq    = u & 1;
            int gy = 2 * yp - 1 + r;
            if ((unsigned)gy < 128u) {
                const u16* g = feaT +
                    (((((size_t)b * 128 + gy) * 16 + (2 * C + ch_lo)) * 2 + cg) * 128 + xq * 64) * 8
                    + (size_t)lane * 8;
                async_load16(g, ldsb + ((r * 4 + ch_lo * 2 + cg) * 128 + xq * 64) * 8);
            }
        }
    };

    f16v acc[4][4];
    #pragma unroll
    for (int i = 0; i < 4; ++i)
        #pragma unroll
        for (int j = 0; j < 4; ++j) acc[i][j] = (f16v)0.0f;

    // A-fragment ring: distance-3 over steps, 18 % 3 == 0 -> static ring index
    s8v fr[3][4];

    // prologue: stage first chunk (= phase), preload its steps 0..2
    stage(0, phase);
    #pragma unroll
    for (int g = 0; g < 3; ++g)
        #pragma unroll
        for (int i = 0; i < 4; ++i) fr[g][i] = loadA(g >> 1, i, phase * 2 + (g & 1));
    __syncthreads();

    #pragma unroll 1
    for (int chi = 0; chi < 8; ++chi) {
        const int ch  = (chi + phase) & 7;           // rotated chunk order
        const int chn = (ch + 1) & 7;                // next chunk
        const u16* basep = &lds[chi & 1][0];

        // B read helper: kh,kw,j,cib compile-time under full unroll
        auto readB = [&](int kh, int kw, int j, int cib) -> s8v {
            const u16* p;
            if (j == 0 && kw == 0)      p = basep + bqL[kh] + cib * 2048;
            else if (j == 3 && kw == 2) p = basep + bqR[kh] + cib * 2048;
            else                        p = basep + rb[kh] + (cib * 2048 + j * 256 + kw * 8);
            return *(const s8v*)p;
        };

        // B double-buffer: step s+1's reads issued during step s's MFMAs.
        s8v bfrE[4], bfrO[4];
        #pragma unroll
        for (int j = 0; j < 4; ++j) bfrE[j] = readB(0, 0, j, 0);   // step 0 fresh

        #pragma unroll
        for (int s = 0; s < 18; ++s) {
            const int t   = s >> 1;
            const int kh  = t / 3;
            const int sn  = s + 1;                    // next step (if s<17)
            const int tn  = sn >> 1;
            const int khn = tn / 3, kwn = tn % 3;
            const int cibn = sn & 1;

            if ((s & 1) == 0) {
                if (s < 17) {
                    #pragma unroll
                    for (int j = 0; j < 4; ++j) bfrO[j] = readB(khn, kwn, j, cibn);
                }
                if (rokU[kh]) {
                    #pragma unroll
                    for (int i = 0; i < 4; ++i)
                        #pragma unroll
                        for (int j = 0; j < 4; ++j)
                            acc[i][j] = __builtin_amdgcn_mfma_f32_32x32x16_bf16(
                                fr[s % 3][i], bfrE[j], acc[i][j], 0, 0, 0);
                }
            } else {
                if (s < 17) {
                    #pragma unroll
                    for (int j = 0; j < 4; ++j) bfrE[j] = readB(khn, kwn, j, cibn);
                }
                if (rokU[kh]) {
                    #pragma unroll
                    for (int i = 0; i < 4; ++i)
                        #pragma unroll
                        for (int j = 0; j < 4; ++j)
                            acc[i][j] = __builtin_amdgcn_mfma_f32_32x32x16_bf16(
                                fr[s % 3][i], bfrO[j], acc[i][j], 0, 0, 0);
                }
            }

            // stage next chunk at s==6 (before the s6 A-refill) so the s9
            // refill-consume wait drains the stage DMAs (vmcnt(12) proof).
            if (s == 6 && chi < 7) {
                __builtin_amdgcn_sched_barrier(0);
                stage((chi + 1) & 1, chn);
                __builtin_amdgcn_sched_barrier(0);
            }

            // A-ring refill: slot s%3 <- fragments needed 3 steps ahead.
            // (after the MFMA block: it overwrites fr[s%3])
            if (s < 15) {
                const int s3 = s + 3;
                #pragma unroll
                for (int i = 0; i < 4; ++i)
                    fr[s % 3][i] = loadA(s3 >> 1, i, ch * 2 + (s3 & 1));
            } else if (chi < 7) {
                const int s3 = s - 15;                // next chunk steps 0..2
                #pragma unroll
                for (int i = 0; i < 4; ++i)
                    fr[s % 3][i] = loadA(s3 >> 1, i, chn * 2 + (s3 & 1));
            }
        }

        if (chi < 7) {
            // counted-vmcnt barrier (T4): the 12 next-chunk A-refills
            // (steps 15-17) stay in flight; everything older completes.
            asm volatile("s_waitcnt vmcnt(12)" ::: "memory");
            __builtin_amdgcn_sched_barrier(0);
            __builtin_amdgcn_s_barrier();
            __builtin_amdgcn_sched_barrier(0);
        }
    }

    // epilogue: C/D layout col(n=pixel)=lane&31, row(m=co)=(reg&3)+8*(reg>>2)+4*(lane>>5)
    const int y_out = 2 * yp + ywv;
    #pragma unroll
    for (int i = 0; i < 4; ++i) {
        #pragma unroll
        for (int j = 0; j < 4; ++j) {
            #pragma unroll
            for (int reg = 0; reg < 16; ++reg) {
                int co = mw * 128 + i * 32 + (reg & 3) + 8 * (reg >> 2) + 4 * l5;
                int x  = j * 32 + l31;
                out[(((size_t)(b * 256 + co) * 128 + y_out) * 128) + x] = acc[i][j][reg];
            }
        }
    }
}

// ---------- launch ----------
extern "C" void kernel_launch(void* const* d_in, const int* in_sizes, int n_in,
                              void* d_out, int out_size, void* d_ws, size_t ws_size,
                              hipStream_t stream) {
    const float* fea       = (const float*)d_in[0];
    const float* norm_feat = (const float*)d_in[1];
    const float* mod_w     = (const float*)d_in[2];
    const float* mod_b     = (const float*)d_in[3];
    const float* weight    = (const float*)d_in[4];
    float* out = (float*)d_out;

    // workspace: Wmod bf16 = 9 MiB, then feaT bf16 = 64 MiB.
    // style (8 KiB fp32) lives at the head of the feaT region (serialized reuse).
    u16* Wmod = (u16*)d_ws;
    u16* feaT = (u16*)((char*)d_ws + 9u * 1024u * 1024u);
    float* style = (float*)feaT;

    style_kernel<<<dim3(8), 256, 0, stream>>>(norm_feat, mod_w, mod_b, style);
    modulate_kernel<<<dim3(256, 8), 256, 0, stream>>>(style, weight, Wmod);
    transpose_kernel<<<dim3(128, 4, 8), 256, 0, stream>>>(fea, feaT);
    conv_mfma<<<dim3(64, 8), 256, 0, stream>>>(Wmod, feaT, out);
}